// Round 10
// baseline (4985.477 us; speedup 1.0000x reference)
//
#include <hip/hip_runtime.h>
#include <hip/hip_bf16.h>
#include <hip/hip_fp16.h>
#include <stdint.h>

#define B_ 128
#define S_ 512
#define E_ 256
#define H2_ 512
#define G_ 1024      // 4*E
#define DG_ 2048     // 4*H2
#define M_ (B_*S_)   // 65536

typedef float f32x4 __attribute__((ext_vector_type(4)));
typedef short s16x8 __attribute__((ext_vector_type(8)));
typedef _Float16 h16x2 __attribute__((ext_vector_type(2)));

__device__ __forceinline__ float sigm(float x){ return 1.f/(1.f+__expf(-x)); }
__device__ __forceinline__ float tanh_f(float x){ return 1.f - 2.f/(__expf(2.f*x)+1.f); }

// ---------------- fp8 e4m3fn encode ----------------
__device__ __forceinline__ uint32_t enc_e4m3(float f){
  uint32_t u = __float_as_uint(f);
  uint32_t s = (u >> 24) & 0x80u;
  float af = fabsf(f);
  if (!(af > 0.f)) return s;
  if (af >= 448.f) return s | 0x7Eu;
  int ex = (int)((u >> 23) & 0xFF) - 127;
  uint32_t man = u & 0x7FFFFFu;
  int bexp = ex + 7;
  if (bexp <= 0){
    uint32_t qi = (uint32_t)rintf(af * 512.f);
    if (qi > 8u) qi = 8u;
    return s | qi;
  }
  uint32_t keep = man >> 20;
  uint32_t rest = man & 0xFFFFFu;
  const uint32_t half = 0x80000u;
  if (rest > half || (rest == half && (keep & 1u))) keep++;
  if (keep == 8u){ keep = 0u; bexp++; }
  if (bexp >= 16) return s | 0x7Eu;
  if (bexp == 15 && keep == 7u) keep = 6u; // avoid NaN encoding
  return s | ((uint32_t)bexp << 3) | keep;
}

__device__ __forceinline__ uint32_t f32_to_fp8_byte(float v){
#if __has_builtin(__builtin_amdgcn_cvt_pk_fp8_f32)
  int pk = __builtin_amdgcn_cvt_pk_fp8_f32(v, v, 0, false);
  return (uint32_t)pk & 0xFFu;
#else
  return enc_e4m3(v);
#endif
}

__device__ __forceinline__ float dot2_f16(uint32_t a, uint32_t b, float acc){
#if __has_builtin(__builtin_amdgcn_fdot2)
  return __builtin_amdgcn_fdot2(__builtin_bit_cast(h16x2,a), __builtin_bit_cast(h16x2,b), acc, false);
#else
  __half2 ah = __builtin_bit_cast(__half2, a), bh = __builtin_bit_cast(__half2, b);
  float2 af = __half22float2(ah), bf = __half22float2(bh);
  return fmaf(af.x, bf.x, fmaf(af.y, bf.y, acc));
#endif
}

// ---------------- weight prep ----------------
__global__ __launch_bounds__(512) void k_prep_enc(
    const float* __restrict__ wf, const float* __restrict__ wb,
    const float* __restrict__ bihf, const float* __restrict__ bhhf,
    const float* __restrict__ bihb, const float* __restrict__ bhhb,
    ushort* __restrict__ Wenc, float* __restrict__ bsum){
  int n = blockIdx.x, d = threadIdx.x;
  const float* src = (n < G_) ? (wf + (size_t)n*H2_) : (wb + (size_t)(n-G_)*H2_);
  __hip_bfloat16 h = __float2bfloat16(src[d]);
  Wenc[(size_t)n*H2_ + d] = __builtin_bit_cast(ushort, h);
  if (d == 0) bsum[n] = (n < G_) ? (bihf[n] + bhhf[n]) : (bihb[n-G_] + bhhb[n-G_]);
}

// Whh fp8, frag-major packed. Tile tl = uh*4+gt of wave wid covers gate rows
//   row = gt*256 + wid*32 + uh*16 + (lane&15)
// so after MFMA each lane holds all 4 gates of its (chain, unit) pairs.
__global__ __launch_bounds__(64) void k_prep_whh_pk(
    const float* __restrict__ whf, const float* __restrict__ whb, uint8_t* __restrict__ Wp){
  int bid = blockIdx.x;            // 0..511 = ((d*8+wid)*8+tl)*4+p
  int lane = threadIdx.x;          // 0..63
  int d   = bid >> 8;
  int rem = bid & 255;
  int wid = rem >> 5;
  int tl  = (rem >> 2) & 7;
  int p   = rem & 3;
  int gt = tl & 3, uh = tl >> 2;
  const float* src = d ? whb : whf;
  int row = gt*256 + wid*32 + uh*16 + (lane & 15);
  int hk  = (lane >> 4) * 8;
  uint8_t bytes[16];
  #pragma unroll
  for (int e = 0; e < 8; ++e){
    bytes[e]     = (uint8_t)enc_e4m3(src[(size_t)row*E_ + (2*p)*32   + hk + e]);
    bytes[8 + e] = (uint8_t)enc_e4m3(src[(size_t)row*E_ + (2*p+1)*32 + hk + e]);
  }
  uint8_t* dst = Wp + ((size_t)bid)*1024 + lane*16;
  *(uint4*)dst = *(const uint4*)bytes;
}

__global__ __launch_bounds__(64) void k_prep_dec(
    const float* __restrict__ wd, const float* __restrict__ bih, const float* __restrict__ bhh,
    uint4* __restrict__ wdt, float* __restrict__ bsumd){
  int row = blockIdx.x, u = threadIdx.x; // u in [0,64)
  const float* src = wd + (size_t)row*H2_ + u*8;
  union { _Float16 h[8]; uint4 q; } pk;
  #pragma unroll
  for (int i=0;i<8;i++) pk.h[i] = (_Float16)src[i];
  wdt[(size_t)u*DG_ + row] = pk.q;
  if (u == 0) bsumd[row] = bih[row] + bhh[row];
}

// ---------------- input stats ----------------
__global__ __launch_bounds__(512) void k_xstat(
    const float* __restrict__ X, float* __restrict__ SX, float* __restrict__ SX2){
  int b = blockIdx.x, d = threadIdx.x;
  const float* xb = X + (size_t)b*S_*H2_;
  float s=0.f, s2=0.f;
  for (int t=0;t<S_;++t){ float v = xb[(size_t)t*H2_ + d]; s += v; s2 = fmaf(v,v,s2); }
  SX[(size_t)b*H2_+d]=s; SX2[(size_t)b*H2_+d]=s2;
}

// ---------------- pre-GEMM, transposed output ----------------
// preT[t][n(0..2047)][b(0..127)] bf16. Block = (n-tile 128, t). A-tile rows =
// 128 chains b at fixed t (X rows m=b*512+t). Epilogue transposes C through
// LDS so the b-contiguous stores are coalesced.
__global__ __launch_bounds__(256) void k_gemm_pre_t(
    const float* __restrict__ X, const ushort* __restrict__ Wenc,
    const float* __restrict__ bsum, ushort* __restrict__ preT){
  __shared__ __align__(16) ushort smem[128*130];   // 33.3 KB (As|Bs then trans)
  ushort (*As)[64] = (ushort (*)[64])(smem);
  ushort (*Bs)[64] = (ushort (*)[64])(smem + 8192);
  int n0 = blockIdx.x * 128;
  int tt = blockIdx.y;
  int tid = threadIdx.x, lane = tid & 63, wq = tid >> 6;
  int wr = wq >> 1, wc = wq & 1;
  f32x4 acc[4][4] = {};
  for (int kt=0; kt<8; ++kt){
    int k0 = kt*64;
    #pragma unroll
    for (int it=0; it<4; ++it){
      int slot = tid + it*256;
      int r = slot >> 3, c8 = (slot & 7)*8;
      const float* ap = X + ((size_t)(r*512 + tt))*512 + k0 + c8;
      float4 a0 = *(const float4*)ap;
      float4 a1 = *(const float4*)(ap+4);
      union { __hip_bfloat16 h[8]; uint4 q; } pk;
      pk.h[0]=__float2bfloat16(a0.x); pk.h[1]=__float2bfloat16(a0.y);
      pk.h[2]=__float2bfloat16(a0.z); pk.h[3]=__float2bfloat16(a0.w);
      pk.h[4]=__float2bfloat16(a1.x); pk.h[5]=__float2bfloat16(a1.y);
      pk.h[6]=__float2bfloat16(a1.z); pk.h[7]=__float2bfloat16(a1.w);
      *(uint4*)&As[r][c8] = pk.q;
      *(uint4*)&Bs[r][c8] = *(const uint4*)(Wenc + (size_t)(n0+r)*512 + k0 + c8);
    }
    __syncthreads();
    #pragma unroll
    for (int kk=0; kk<2; ++kk){
      int krow = kk*32 + (lane>>4)*8;
      s16x8 af[4], bf[4];
      #pragma unroll
      for (int mi=0;mi<4;mi++) af[mi] = *(const s16x8*)&As[wr*64+mi*16+(lane&15)][krow];
      #pragma unroll
      for (int ni=0;ni<4;ni++) bf[ni] = *(const s16x8*)&Bs[wc*64+ni*16+(lane&15)][krow];
      #pragma unroll
      for (int mi=0;mi<4;mi++){
        #pragma unroll
        for (int ni=0;ni<4;ni++)
          acc[mi][ni] = __builtin_amdgcn_mfma_f32_16x16x32_bf16(af[mi], bf[ni], acc[mi][ni], 0,0,0);
      }
    }
    __syncthreads();
  }
  // epilogue: bias + bf16, C[b][n] -> smem[n_l*130 + b] (pad 130: conflict-free)
  #pragma unroll
  for (int ni=0; ni<4; ++ni){
    int n_l = wc*64 + ni*16 + (lane&15);
    float bs = bsum[n0 + n_l];
    #pragma unroll
    for (int mi=0; mi<4; ++mi){
      int bb = wr*64 + mi*16 + (lane>>4)*4;
      #pragma unroll
      for (int r2=0;r2<4;r2++){
        __hip_bfloat16 hv = __float2bfloat16(acc[mi][ni][r2] + bs);
        smem[n_l*130 + bb + r2] = __builtin_bit_cast(ushort, hv);
      }
    }
  }
  __syncthreads();
  #pragma unroll
  for (int it=0; it<64; ++it){
    int n_l = it*2 + (tid>>7);
    int b = tid & 127;
    preT[((size_t)tt*2048 + n0 + n_l)*128 + b] = smem[n_l*130 + b];
  }
}

// ---------------- encoder recurrence v10: in-register gate combine ----------------
// 16 wgs; wg = (dir, 16 chains b0..b0+15). Per step: 64 fp8 MFMAs/wave with
// re-packed W (lane ends with all 4 gates of its 8 (chain,unit) pairs in acc),
// pre fetched per-lane from preT (b64, HBM-latency hidden under W stream),
// gates lane-local, h (fp8) double-buffered in LDS. ONE barrier per step.
__global__ __launch_bounds__(512) void k_enc_mfma(
    const ushort* __restrict__ preT, const uint8_t* __restrict__ Wp,
    float* __restrict__ SH, float* __restrict__ x0){
  int wg = blockIdx.x;            // 0..15
  int dir = wg >> 3;
  int b0 = (wg & 7) * 16;
  int t = threadIdx.x, lane = t & 63, wid = t >> 6;
  __shared__ __align__(16) uint8_t hb[2][16*264];
  for (int i=t; i<2*16*264; i+=512) ((uint8_t*)hb)[i] = 0;
  int frow = lane & 15;
  int mb = (lane >> 4) * 4;
  int u0 = wid*32 + frow;
  float c_st[8] = {0,0,0,0,0,0,0,0};
  float sumh[8] = {0,0,0,0,0,0,0,0};
  const uint4* wp0 = (const uint4*)(Wp + ((size_t)(dir*8 + wid))*32768);
  __syncthreads();
  int pb = 0;
  for (int s=0; s<S_; ++s){
    int ts = dir ? (S_-1-s) : s;
    // pre loads first (HBM latency hides under the W stream + MFMAs)
    const ushort* pbase = preT + ((size_t)ts*2048 + dir*1024)*128 + b0 + mb;
    uint2 pv[4][2];
    #pragma unroll
    for (int gt=0; gt<4; ++gt)
      #pragma unroll
      for (int uh=0; uh<2; ++uh)
        pv[gt][uh] = *(const uint2*)(pbase + (size_t)(gt*256 + u0 + uh*16)*128);
    // A-frags (fp8 h) from LDS
    long long a_ll[8];
    {
      const uint8_t* ar = &hb[pb][frow*264 + ((lane>>4)*8)];
      #pragma unroll
      for (int kk=0; kk<8; ++kk){
        uint2 v = *(const uint2*)(ar + kk*32);
        a_ll[kk] = (((long long)v.y) << 32) | (unsigned int)v.x;
      }
    }
    // MFMAs: B streamed coalesced from L2-resident packed fp8 W
    const uint4* wl = wp0;
    asm volatile("" : "+v"(wl));       // anti-LICM: re-issue W loads each step
    f32x4 acc[8] = {};
    #pragma unroll
    for (int tl=0; tl<8; ++tl){
      #pragma unroll
      for (int p=0; p<4; ++p){
        uint4 q = wl[(tl*4 + p)*64 + lane];
        long long bf0 = (((long long)q.y) << 32) | (unsigned int)q.x;
        long long bf1 = (((long long)q.w) << 32) | (unsigned int)q.z;
        acc[tl] = __builtin_amdgcn_mfma_f32_16x16x32_fp8_fp8(a_ll[2*p],   bf0, acc[tl], 0,0,0);
        acc[tl] = __builtin_amdgcn_mfma_f32_16x16x32_fp8_fp8(a_ll[2*p+1], bf1, acc[tl], 0,0,0);
      }
    }
    // gates + state update, fully lane-local
    int wx0 = (dir==0 && s==S_-1) || (dir==1 && s==0);
    #pragma unroll
    for (int uh=0; uh<2; ++uh){
      #pragma unroll
      for (int r=0; r<4; ++r){
        int si = uh*4 + r;
        unsigned w0 = (r < 2) ? pv[0][uh].x : pv[0][uh].y;
        unsigned w1 = (r < 2) ? pv[1][uh].x : pv[1][uh].y;
        unsigned w2 = (r < 2) ? pv[2][uh].x : pv[2][uh].y;
        unsigned w3 = (r < 2) ? pv[3][uh].x : pv[3][uh].y;
        unsigned sh16 = (r & 1) ? 16u : 0u;
        float gi = acc[uh*4+0][r] + __uint_as_float(((w0 >> sh16) & 0xFFFFu) << 16);
        float gf = acc[uh*4+1][r] + __uint_as_float(((w1 >> sh16) & 0xFFFFu) << 16);
        float gg = acc[uh*4+2][r] + __uint_as_float(((w2 >> sh16) & 0xFFFFu) << 16);
        float go = acc[uh*4+3][r] + __uint_as_float(((w3 >> sh16) & 0xFFFFu) << 16);
        float cn = sigm(gf)*c_st[si] + sigm(gi)*tanh_f(gg);
        float hn = sigm(go)*tanh_f(cn);
        c_st[si] = cn;
        sumh[si] += hn;
        hb[pb^1][(mb+r)*264 + u0 + uh*16] = (uint8_t)f32_to_fp8_byte(hn);
        if (wx0) x0[(size_t)(b0+mb+r)*H2_ + dir*E_ + u0 + uh*16] = hn;
      }
    }
    __syncthreads();
    pb ^= 1;
  }
  #pragma unroll
  for (int uh=0; uh<2; ++uh)
    #pragma unroll
    for (int r=0; r<4; ++r)
      SH[((size_t)dir*B_ + b0 + mb + r)*E_ + u0 + uh*16] = sumh[uh*4+r];
}

// ---------------- decoder + ae_loss: 128 wgs = b, 512 thr = hidden dim ----------------
#define EPS_CONV 2e-6f
__global__ __launch_bounds__(512) void k_dec(
    const float* __restrict__ X, const uint4* __restrict__ wdt,
    const float* __restrict__ bsumd, const float* __restrict__ x0,
    const float* __restrict__ SX, const float* __restrict__ SX2,
    float* __restrict__ loss_b){
  int b = blockIdx.x, j = threadIdx.x;
  __shared__ _Float16 hl[512];
  __shared__ float red[512];
  float h = x0[(size_t)b*H2_ + j];
  hl[j] = (_Float16)h;
  float bi = bsumd[j], bg = bsumd[j+1024], bo = bsumd[j+1536];
  float sxp = 0.f, x2p = 0.f, lacc = 0.f;
  const float* xb = X + (size_t)b*S_*H2_;
  int done = S_;
  __syncthreads();
  for (int s=0; s<S_; ++s){
    float ai = bi, ag = bg, ao = bo;
    const uint4* hp = (const uint4*)hl;
    const uint4* wi = wdt + j;
    const uint4* wgp = wdt + j + 1024;
    const uint4* wo = wdt + j + 1536;
    #pragma unroll 8
    for (int u=0; u<64; ++u){
      uint4 hv = hp[u];
      uint4 a = wi[(size_t)u*DG_];
      uint4 g = wgp[(size_t)u*DG_];
      uint4 o = wo[(size_t)u*DG_];
      ai = dot2_f16(a.x, hv.x, ai); ai = dot2_f16(a.y, hv.y, ai);
      ai = dot2_f16(a.z, hv.z, ai); ai = dot2_f16(a.w, hv.w, ai);
      ag = dot2_f16(g.x, hv.x, ag); ag = dot2_f16(g.y, hv.y, ag);
      ag = dot2_f16(g.z, hv.z, ag); ag = dot2_f16(g.w, hv.w, ag);
      ao = dot2_f16(o.x, hv.x, ao); ao = dot2_f16(o.y, hv.y, ao);
      ao = dot2_f16(o.w, hv.w, ao); ao = dot2_f16(o.z, hv.z, ao);
    }
    float cc = sigm(ai) * tanh_f(ag);
    float hn = sigm(ao) * tanh_f(cc);
    float xv = xb[(size_t)s*H2_ + j];
    float dd = xv - hn;
    lacc += dd*dd; sxp += xv; x2p = fmaf(xv,xv,x2p);
    float delta = fabsf(hn - h);
    h = hn;
    __syncthreads();                      // all dot-reads of old hl done
    hl[j] = (_Float16)h;
    if (__syncthreads_count(delta > EPS_CONV) == 0){ done = s+1; break; }
  }
  if (done < S_){
    size_t o = (size_t)b*H2_ + j;
    float rx = SX[o] - sxp, rx2 = SX2[o] - x2p;
    float rem = (float)(S_ - done);
    lacc += rx2 - 2.f*h*rx + rem*h*h;
  }
  red[j] = lacc;
  __syncthreads();
  for (int st=256; st>0; st>>=1){
    if (j < st) red[j] += red[j+st];
    __syncthreads();
  }
  if (j == 0) loss_b[b] = red[0];
}

// ---------------- output head ----------------
__global__ __launch_bounds__(256) void k_out(
    const float* __restrict__ SX, const float* __restrict__ SH,
    const float* __restrict__ outW, const float* __restrict__ outWb,
    const float* __restrict__ loss_b, float* __restrict__ out){
  int b = blockIdx.x, o = threadIdx.x;
  __shared__ float pooled[512];
  for (int d=o; d<512; d+=256){
    float v = SX[(size_t)b*H2_ + d];
    v += (d < E_) ? SH[(size_t)b*E_ + d] : SH[(size_t)(B_ + b)*E_ + (d - E_)];
    pooled[d] = v;
  }
  __syncthreads();
  const float4* w4 = (const float4*)(outW + (size_t)o*H2_);
  const float4* p4 = (const float4*)pooled;
  float acc = outWb[o];
  #pragma unroll 16
  for (int i=0;i<128;i++){
    float4 w = w4[i], p = p4[i];
    acc = fmaf(w.x,p.x,acc); acc = fmaf(w.y,p.y,acc);
    acc = fmaf(w.z,p.z,acc); acc = fmaf(w.w,p.w,acc);
  }
  out[(size_t)b*256 + o] = acc;
  if (b == 0 && o == 0){
    float L = 0.f;
    for (int i=0;i<B_;i++) L += loss_b[i];
    out[32768] = L / 33554432.f;
  }
}

extern "C" void kernel_launch(void* const* d_in, const int* in_sizes, int n_in,
                              void* d_out, int out_size, void* d_ws, size_t ws_size,
                              hipStream_t stream) {
  const float* X     = (const float*)d_in[0];
  const float* Wihf  = (const float*)d_in[1];
  const float* Whhf  = (const float*)d_in[2];
  const float* bihf  = (const float*)d_in[3];
  const float* bhhf  = (const float*)d_in[4];
  const float* Wihb  = (const float*)d_in[5];
  const float* Whhb  = (const float*)d_in[6];
  const float* bihb  = (const float*)d_in[7];
  const float* bhhb  = (const float*)d_in[8];
  const float* Wdec  = (const float*)d_in[9];
  const float* dbih  = (const float*)d_in[10];
  const float* dbhh  = (const float*)d_in[11];
  // d_in[12..15]: attW/attW_b/attU/attU_b are mathematically dead (softmax over size-1 axis)
  const float* outW  = (const float*)d_in[16];
  const float* outWb = (const float*)d_in[17];
  float* out = (float*)d_out;

  char* ws = (char*)d_ws;
  size_t off = 0;
  auto alloc = [&](size_t bytes){ void* p = ws + off; off += (bytes + 255) & ~(size_t)255; return p; };
  ushort* preT         = (ushort*)alloc((size_t)S_*DG_*B_*2);        // 268 MB [t][n][b]
  ushort* Wenc         = (ushort*)alloc((size_t)DG_*H2_*2);
  float* bsum          = (float*)alloc((size_t)DG_*4);
  uint8_t* Wp          = (uint8_t*)alloc((size_t)2*G_*E_);           // 512 KB packed fp8 Whh
  uint4* wdt           = (uint4*)alloc((size_t)64*DG_*16);
  float* bsumd         = (float*)alloc((size_t)DG_*4);
  float* SX            = (float*)alloc((size_t)B_*H2_*4);
  float* SX2           = (float*)alloc((size_t)B_*H2_*4);
  float* SH            = (float*)alloc((size_t)2*B_*E_*4);
  float* x0            = (float*)alloc((size_t)B_*H2_*4);
  float* loss_b        = (float*)alloc((size_t)B_*4);

  hipLaunchKernelGGL(k_prep_enc, dim3(DG_), dim3(512), 0, stream,
                     Wihf, Wihb, bihf, bhhf, bihb, bhhb, Wenc, bsum);
  hipLaunchKernelGGL(k_prep_whh_pk, dim3(512), dim3(64), 0, stream, Whhf, Whhb, Wp);
  hipLaunchKernelGGL(k_prep_dec, dim3(DG_), dim3(64), 0, stream, Wdec, dbih, dbhh, wdt, bsumd);
  hipLaunchKernelGGL(k_xstat, dim3(B_), dim3(H2_), 0, stream, X, SX, SX2);
  hipLaunchKernelGGL(k_gemm_pre_t, dim3(16, 512), dim3(256), 0, stream, X, Wenc, bsum, preT);
  hipLaunchKernelGGL(k_enc_mfma, dim3(16), dim3(512), 0, stream, preT, Wp, SH, x0);
  hipLaunchKernelGGL(k_dec, dim3(B_), dim3(512), 0, stream, X, wdt, bsumd, x0, SX, SX2, loss_b);
  hipLaunchKernelGGL(k_out, dim3(B_), dim3(256), 0, stream, SX, SH, outW, outWb, loss_b, out);
}

// Round 11
// 3690.604 us; speedup vs baseline: 1.3509x; 1.3509x over previous
//
#include <hip/hip_runtime.h>
#include <hip/hip_bf16.h>
#include <hip/hip_fp16.h>
#include <stdint.h>

#define B_ 128
#define S_ 512
#define E_ 256
#define H2_ 512
#define G_ 1024      // 4*E
#define DG_ 2048     // 4*H2
#define M_ (B_*S_)   // 65536

typedef float f32x4 __attribute__((ext_vector_type(4)));
typedef short s16x8 __attribute__((ext_vector_type(8)));
typedef _Float16 h16x2 __attribute__((ext_vector_type(2)));

__device__ __forceinline__ float sigm(float x){ return 1.f/(1.f+__expf(-x)); }
__device__ __forceinline__ float tanh_f(float x){ return 1.f - 2.f/(__expf(2.f*x)+1.f); }

// async global->LDS, 16B per lane (LDS dest must be wave-uniform base; HW adds lane*16)
__device__ __forceinline__ void gload_lds16(const void* g, void* l){
  __builtin_amdgcn_global_load_lds(
      (const __attribute__((address_space(1))) void*)g,
      (__attribute__((address_space(3))) void*)l,
      16, 0, 0);
}

// ---------------- fp8 e4m3fn encode ----------------
__device__ __forceinline__ uint32_t enc_e4m3(float f){
  uint32_t u = __float_as_uint(f);
  uint32_t s = (u >> 24) & 0x80u;
  float af = fabsf(f);
  if (!(af > 0.f)) return s;
  if (af >= 448.f) return s | 0x7Eu;
  int ex = (int)((u >> 23) & 0xFF) - 127;
  uint32_t man = u & 0x7FFFFFu;
  int bexp = ex + 7;
  if (bexp <= 0){
    uint32_t qi = (uint32_t)rintf(af * 512.f);
    if (qi > 8u) qi = 8u;
    return s | qi;
  }
  uint32_t keep = man >> 20;
  uint32_t rest = man & 0xFFFFFu;
  const uint32_t half = 0x80000u;
  if (rest > half || (rest == half && (keep & 1u))) keep++;
  if (keep == 8u){ keep = 0u; bexp++; }
  if (bexp >= 16) return s | 0x7Eu;
  if (bexp == 15 && keep == 7u) keep = 6u; // avoid NaN encoding
  return s | ((uint32_t)bexp << 3) | keep;
}

__device__ __forceinline__ uint32_t f32_to_fp8_byte(float v){
#if __has_builtin(__builtin_amdgcn_cvt_pk_fp8_f32)
  int pk = __builtin_amdgcn_cvt_pk_fp8_f32(v, v, 0, false);
  return (uint32_t)pk & 0xFFu;
#else
  return enc_e4m3(v);
#endif
}

__device__ __forceinline__ float dot2_f16(uint32_t a, uint32_t b, float acc){
#if __has_builtin(__builtin_amdgcn_fdot2)
  return __builtin_amdgcn_fdot2(__builtin_bit_cast(h16x2,a), __builtin_bit_cast(h16x2,b), acc, false);
#else
  __half2 ah = __builtin_bit_cast(__half2, a), bh = __builtin_bit_cast(__half2, b);
  float2 af = __half22float2(ah), bf = __half22float2(bh);
  return fmaf(af.x, bf.x, fmaf(af.y, bf.y, acc));
#endif
}

// ---------------- weight prep ----------------
__global__ __launch_bounds__(512) void k_prep_enc(
    const float* __restrict__ wf, const float* __restrict__ wb,
    const float* __restrict__ bihf, const float* __restrict__ bhhf,
    const float* __restrict__ bihb, const float* __restrict__ bhhb,
    ushort* __restrict__ Wenc, float* __restrict__ bsum){
  int n = blockIdx.x, d = threadIdx.x;
  const float* src = (n < G_) ? (wf + (size_t)n*H2_) : (wb + (size_t)(n-G_)*H2_);
  __hip_bfloat16 h = __float2bfloat16(src[d]);
  Wenc[(size_t)n*H2_ + d] = __builtin_bit_cast(ushort, h);
  if (d == 0) bsum[n] = (n < G_) ? (bihf[n] + bhhf[n]) : (bihb[n-G_] + bhhb[n-G_]);
}

// Whh fp8, frag-major packed. Tile tl = uh*4+gt of wave wid covers gate rows
//   row = gt*256 + wid*32 + uh*16 + (lane&15)
// so after MFMA each lane holds all 4 gates of its (chain, unit) pairs.
__global__ __launch_bounds__(64) void k_prep_whh_pk(
    const float* __restrict__ whf, const float* __restrict__ whb, uint8_t* __restrict__ Wp){
  int bid = blockIdx.x;            // 0..511 = ((d*8+wid)*8+tl)*4+p
  int lane = threadIdx.x;          // 0..63
  int d   = bid >> 8;
  int rem = bid & 255;
  int wid = rem >> 5;
  int tl  = (rem >> 2) & 7;
  int p   = rem & 3;
  int gt = tl & 3, uh = tl >> 2;
  const float* src = d ? whb : whf;
  int row = gt*256 + wid*32 + uh*16 + (lane & 15);
  int hk  = (lane >> 4) * 8;
  uint8_t bytes[16];
  #pragma unroll
  for (int e = 0; e < 8; ++e){
    bytes[e]     = (uint8_t)enc_e4m3(src[(size_t)row*E_ + (2*p)*32   + hk + e]);
    bytes[8 + e] = (uint8_t)enc_e4m3(src[(size_t)row*E_ + (2*p+1)*32 + hk + e]);
  }
  uint8_t* dst = Wp + ((size_t)bid)*1024 + lane*16;
  *(uint4*)dst = *(const uint4*)bytes;
}

__global__ __launch_bounds__(64) void k_prep_dec(
    const float* __restrict__ wd, const float* __restrict__ bih, const float* __restrict__ bhh,
    uint4* __restrict__ wdt, float* __restrict__ bsumd){
  int row = blockIdx.x, u = threadIdx.x; // u in [0,64)
  const float* src = wd + (size_t)row*H2_ + u*8;
  union { _Float16 h[8]; uint4 q; } pk;
  #pragma unroll
  for (int i=0;i<8;i++) pk.h[i] = (_Float16)src[i];
  wdt[(size_t)u*DG_ + row] = pk.q;
  if (u == 0) bsumd[row] = bih[row] + bhh[row];
}

// ---------------- input stats ----------------
__global__ __launch_bounds__(512) void k_xstat(
    const float* __restrict__ X, float* __restrict__ SX, float* __restrict__ SX2){
  int b = blockIdx.x, d = threadIdx.x;
  const float* xb = X + (size_t)b*S_*H2_;
  float s=0.f, s2=0.f;
  for (int t=0;t<S_;++t){ float v = xb[(size_t)t*H2_ + d]; s += v; s2 = fmaf(v,v,s2); }
  SX[(size_t)b*H2_+d]=s; SX2[(size_t)b*H2_+d]=s2;
}

// ---------------- pre-GEMM, blocked-transposed output ----------------
// preT[t][wgb(8)][n(0..1023 within dir-half interleaved: actually n 0..2047)][bb(16)]
// layout: element ((t*8 + (b>>4))*2048 + n)*16 + (b&15); per (t, wg-of-16) the
// 2048x16 tile is contiguous (64 KB both dirs; each wg reads its dir's 32 KB half).
__global__ __launch_bounds__(256) void k_gemm_pre_t(
    const float* __restrict__ X, const ushort* __restrict__ Wenc,
    const float* __restrict__ bsum, ushort* __restrict__ preT){
  __shared__ __align__(16) ushort smem[128*130];   // 33.3 KB (As|Bs then trans)
  ushort (*As)[64] = (ushort (*)[64])(smem);
  ushort (*Bs)[64] = (ushort (*)[64])(smem + 8192);
  int n0 = blockIdx.x * 128;
  int tt = blockIdx.y;
  int tid = threadIdx.x, lane = tid & 63, wq = tid >> 6;
  int wr = wq >> 1, wc = wq & 1;
  f32x4 acc[4][4] = {};
  for (int kt=0; kt<8; ++kt){
    int k0 = kt*64;
    #pragma unroll
    for (int it=0; it<4; ++it){
      int slot = tid + it*256;
      int r = slot >> 3, c8 = (slot & 7)*8;
      const float* ap = X + ((size_t)(r*512 + tt))*512 + k0 + c8;
      float4 a0 = *(const float4*)ap;
      float4 a1 = *(const float4*)(ap+4);
      union { __hip_bfloat16 h[8]; uint4 q; } pk;
      pk.h[0]=__float2bfloat16(a0.x); pk.h[1]=__float2bfloat16(a0.y);
      pk.h[2]=__float2bfloat16(a0.z); pk.h[3]=__float2bfloat16(a0.w);
      pk.h[4]=__float2bfloat16(a1.x); pk.h[5]=__float2bfloat16(a1.y);
      pk.h[6]=__float2bfloat16(a1.z); pk.h[7]=__float2bfloat16(a1.w);
      *(uint4*)&As[r][c8] = pk.q;
      *(uint4*)&Bs[r][c8] = *(const uint4*)(Wenc + (size_t)(n0+r)*512 + k0 + c8);
    }
    __syncthreads();
    #pragma unroll
    for (int kk=0; kk<2; ++kk){
      int krow = kk*32 + (lane>>4)*8;
      s16x8 af[4], bf[4];
      #pragma unroll
      for (int mi=0;mi<4;mi++) af[mi] = *(const s16x8*)&As[wr*64+mi*16+(lane&15)][krow];
      #pragma unroll
      for (int ni=0;ni<4;ni++) bf[ni] = *(const s16x8*)&Bs[wc*64+ni*16+(lane&15)][krow];
      #pragma unroll
      for (int mi=0;mi<4;mi++){
        #pragma unroll
        for (int ni=0;ni<4;ni++)
          acc[mi][ni] = __builtin_amdgcn_mfma_f32_16x16x32_bf16(af[mi], bf[ni], acc[mi][ni], 0,0,0);
      }
    }
    __syncthreads();
  }
  // epilogue: bias + bf16, C[b][n] -> smem[n_l*130 + b] (pad 130: conflict-free)
  #pragma unroll
  for (int ni=0; ni<4; ++ni){
    int n_l = wc*64 + ni*16 + (lane&15);
    float bs = bsum[n0 + n_l];
    #pragma unroll
    for (int mi=0; mi<4; ++mi){
      int bb = wr*64 + mi*16 + (lane>>4)*4;
      #pragma unroll
      for (int r2=0;r2<4;r2++){
        __hip_bfloat16 hv = __float2bfloat16(acc[mi][ni][r2] + bs);
        smem[n_l*130 + bb + r2] = __builtin_bit_cast(ushort, hv);
      }
    }
  }
  __syncthreads();
  #pragma unroll
  for (int it=0; it<64; ++it){
    int n_l = it*2 + (tid>>7);
    int b = tid & 127;
    preT[(((size_t)tt*8 + (b>>4))*2048 + n0 + n_l)*16 + (b & 15)] = smem[n_l*130 + b];
  }
}

// ---------------- encoder recurrence v11 ----------------
// v10 lane-local-gate skeleton + two memory-path fixes:
//  * 14/32 W chunks per wave resident in LDS (112 KB, one-time stage;
//    ds_read_b128 lane-consecutive = conflict-free); 18 chunks stream from L2.
//    Both bases laundered per step (anti-LICM, no register hoard -> no spill).
//  * pre staged per step via async global_load_lds into pbuf (32 KB), issued at
//    loop top, drained by the pre-gate barrier after the MFMA phase ->
//    HBM latency hidden; blocked preT layout -> perfectly coalesced, no overfetch.
__global__ __launch_bounds__(512) void k_enc_mfma(
    const ushort* __restrict__ preT, const uint8_t* __restrict__ Wp,
    float* __restrict__ SH, float* __restrict__ x0){
  int wg = blockIdx.x;            // 0..15
  int dir = wg >> 3;
  int b0q = wg & 7;
  int b0 = b0q * 16;
  int t = threadIdx.x, lane = t & 63, wid = t >> 6;
  __shared__ __align__(16) uint4  wlds[8*14*64];    // 112 KB W chunks 0..13 per wave
  __shared__ __align__(16) ushort pbuf[2048*8];     // 32 KB: wg's [n][16] bf16 tile... (n*16+bb)/2
  __shared__ __align__(16) uint8_t hb[2][16*264];   // 8.25 KB

  // one-time W stage (chunks 0..13 of this wave's 32)
  {
    const uint4* src = (const uint4*)(Wp + ((size_t)(dir*8 + wid))*32768);
    #pragma unroll
    for (int c=0; c<14; ++c)
      wlds[(wid*14 + c)*64 + lane] = src[c*64 + lane];
  }
  for (int i=t; i<2*16*264; i+=512) ((uint8_t*)hb)[i] = 0;

  int frow = lane & 15;
  int mb = (lane >> 4) * 4;
  int u0 = wid*32 + frow;
  float c_st[8] = {0,0,0,0,0,0,0,0};
  float sumh[8] = {0,0,0,0,0,0,0,0};
  const uint4* wp0 = (const uint4*)(Wp + ((size_t)(dir*8 + wid))*32768);
  __syncthreads();

  int pb = 0;
  for (int s=0; s<S_; ++s){
    int ts = dir ? (S_-1-s) : s;
    // ---- 1) async pre stage for THIS step (fire-and-forget; drained at barrier) ----
    {
      // wg tile base: ((ts*8 + b0q)*2048 + dir*1024)*16 ushorts; 32 KB contiguous
      const uint8_t* gb = (const uint8_t*)(preT + (((size_t)ts*8 + b0q)*2048 + (size_t)dir*1024)*16);
      uint8_t* lb = (uint8_t*)pbuf;
      #pragma unroll
      for (int c=0; c<4; ++c){
        gload_lds16(gb + (((wid*4 + c)*64 + lane) << 4), lb + (wid*4 + c)*1024);
      }
    }
    // ---- 2) A-frags (fp8 h) from LDS ----
    long long a_ll[8];
    {
      const uint8_t* ar = &hb[pb][frow*264 + ((lane>>4)*8)];
      #pragma unroll
      for (int kk=0; kk<8; ++kk){
        uint2 v = *(const uint2*)(ar + kk*32);
        a_ll[kk] = (((long long)v.y) << 32) | (unsigned int)v.x;
      }
    }
    // ---- 3) MFMAs: 14 chunks from LDS, 18 from L2 (both laundered) ----
    const uint4* wl = wp0;
    const uint4* wl2 = &wlds[(wid*14)*64 + lane];
    asm volatile("" : "+v"(wl), "+v"(wl2));
    f32x4 acc[8] = {};
    #pragma unroll
    for (int tl=0; tl<8; ++tl){
      #pragma unroll
      for (int p=0; p<4; ++p){
        int c = tl*4 + p;
        uint4 q = (c < 14) ? wl2[c*64] : wl[c*64 + lane];
        long long bf0 = (((long long)q.y) << 32) | (unsigned int)q.x;
        long long bf1 = (((long long)q.w) << 32) | (unsigned int)q.z;
        acc[tl] = __builtin_amdgcn_mfma_f32_16x16x32_fp8_fp8(a_ll[2*p],   bf0, acc[tl], 0,0,0);
        acc[tl] = __builtin_amdgcn_mfma_f32_16x16x32_fp8_fp8(a_ll[2*p+1], bf1, acc[tl], 0,0,0);
      }
    }
    __syncthreads();   // drains vmcnt (pbuf ready) + all hb[pb] reads done
    // ---- 4) gates + state update, lane-local; pre from pbuf ----
    int wx0 = (dir==0 && s==S_-1) || (dir==1 && s==0);
    #pragma unroll
    for (int uh=0; uh<2; ++uh){
      int r0 = u0 + uh*16;
      uint2 pvv[4];
      #pragma unroll
      for (int gt=0; gt<4; ++gt)
        pvv[gt] = *(const uint2*)&pbuf[(gt*256 + r0)*16 + mb];
      #pragma unroll
      for (int r=0; r<4; ++r){
        int si = uh*4 + r;
        unsigned w0 = (r < 2) ? pvv[0].x : pvv[0].y;
        unsigned w1 = (r < 2) ? pvv[1].x : pvv[1].y;
        unsigned w2 = (r < 2) ? pvv[2].x : pvv[2].y;
        unsigned w3 = (r < 2) ? pvv[3].x : pvv[3].y;
        unsigned sh16 = (r & 1) ? 16u : 0u;
        float gi = acc[uh*4+0][r] + __uint_as_float(((w0 >> sh16) & 0xFFFFu) << 16);
        float gf = acc[uh*4+1][r] + __uint_as_float(((w1 >> sh16) & 0xFFFFu) << 16);
        float gg = acc[uh*4+2][r] + __uint_as_float(((w2 >> sh16) & 0xFFFFu) << 16);
        float go = acc[uh*4+3][r] + __uint_as_float(((w3 >> sh16) & 0xFFFFu) << 16);
        float cn = sigm(gf)*c_st[si] + sigm(gi)*tanh_f(gg);
        float hn = sigm(go)*tanh_f(cn);
        c_st[si] = cn;
        sumh[si] += hn;
        hb[pb^1][(mb+r)*264 + r0] = (uint8_t)f32_to_fp8_byte(hn);
        if (wx0) x0[(size_t)(b0+mb+r)*H2_ + dir*E_ + r0] = hn;
      }
    }
    __syncthreads();   // hb[pb^1] + pbuf reads complete before next stage
    pb ^= 1;
  }
  #pragma unroll
  for (int uh=0; uh<2; ++uh)
    #pragma unroll
    for (int r=0; r<4; ++r)
      SH[((size_t)dir*B_ + b0 + mb + r)*E_ + u0 + uh*16] = sumh[uh*4+r];
}

// ---------------- decoder + ae_loss: 128 wgs = b, 512 thr = hidden dim ----------------
#define EPS_CONV 2e-6f
__global__ __launch_bounds__(512) void k_dec(
    const float* __restrict__ X, const uint4* __restrict__ wdt,
    const float* __restrict__ bsumd, const float* __restrict__ x0,
    const float* __restrict__ SX, const float* __restrict__ SX2,
    float* __restrict__ loss_b){
  int b = blockIdx.x, j = threadIdx.x;
  __shared__ _Float16 hl[512];
  __shared__ float red[512];
  float h = x0[(size_t)b*H2_ + j];
  hl[j] = (_Float16)h;
  float bi = bsumd[j], bg = bsumd[j+1024], bo = bsumd[j+1536];
  float sxp = 0.f, x2p = 0.f, lacc = 0.f;
  const float* xb = X + (size_t)b*S_*H2_;
  int done = S_;
  __syncthreads();
  for (int s=0; s<S_; ++s){
    float ai = bi, ag = bg, ao = bo;
    const uint4* hp = (const uint4*)hl;
    const uint4* wi = wdt + j;
    const uint4* wgp = wdt + j + 1024;
    const uint4* wo = wdt + j + 1536;
    #pragma unroll 8
    for (int u=0; u<64; ++u){
      uint4 hv = hp[u];
      uint4 a = wi[(size_t)u*DG_];
      uint4 g = wgp[(size_t)u*DG_];
      uint4 o = wo[(size_t)u*DG_];
      ai = dot2_f16(a.x, hv.x, ai); ai = dot2_f16(a.y, hv.y, ai);
      ai = dot2_f16(a.z, hv.z, ai); ai = dot2_f16(a.w, hv.w, ai);
      ag = dot2_f16(g.x, hv.x, ag); ag = dot2_f16(g.y, hv.y, ag);
      ag = dot2_f16(g.z, hv.z, ag); ag = dot2_f16(g.w, hv.w, ag);
      ao = dot2_f16(o.x, hv.x, ao); ao = dot2_f16(o.y, hv.y, ao);
      ao = dot2_f16(o.z, hv.z, ao); ao = dot2_f16(o.w, hv.w, ao);
    }
    float cc = sigm(ai) * tanh_f(ag);
    float hn = sigm(ao) * tanh_f(cc);
    float xv = xb[(size_t)s*H2_ + j];
    float dd = xv - hn;
    lacc += dd*dd; sxp += xv; x2p = fmaf(xv,xv,x2p);
    float delta = fabsf(hn - h);
    h = hn;
    __syncthreads();                      // all dot-reads of old hl done
    hl[j] = (_Float16)h;
    if (__syncthreads_count(delta > EPS_CONV) == 0){ done = s+1; break; }
  }
  if (done < S_){
    size_t o = (size_t)b*H2_ + j;
    float rx = SX[o] - sxp, rx2 = SX2[o] - x2p;
    float rem = (float)(S_ - done);
    lacc += rx2 - 2.f*h*rx + rem*h*h;
  }
  red[j] = lacc;
  __syncthreads();
  for (int st=256; st>0; st>>=1){
    if (j < st) red[j] += red[j+st];
    __syncthreads();
  }
  if (j == 0) loss_b[b] = red[0];
}

// ---------------- output head ----------------
__global__ __launch_bounds__(256) void k_out(
    const float* __restrict__ SX, const float* __restrict__ SH,
    const float* __restrict__ outW, const float* __restrict__ outWb,
    const float* __restrict__ loss_b, float* __restrict__ out){
  int b = blockIdx.x, o = threadIdx.x;
  __shared__ float pooled[512];
  for (int d=o; d<512; d+=256){
    float v = SX[(size_t)b*H2_ + d];
    v += (d < E_) ? SH[(size_t)b*E_ + d] : SH[(size_t)(B_ + b)*E_ + (d - E_)];
    pooled[d] = v;
  }
  __syncthreads();
  const float4* w4 = (const float4*)(outW + (size_t)o*H2_);
  const float4* p4 = (const float4*)pooled;
  float acc = outWb[o];
  #pragma unroll 16
  for (int i=0;i<128;i++){
    float4 w = w4[i], p = p4[i];
    acc = fmaf(w.x,p.x,acc); acc = fmaf(w.y,p.y,acc);
    acc = fmaf(w.z,p.z,acc); acc = fmaf(w.w,p.w,acc);
  }
  out[(size_t)b*256 + o] = acc;
  if (b == 0 && o == 0){
    float L = 0.f;
    for (int i=0;i<B_;i++) L += loss_b[i];
    out[32768] = L / 33554432.f;
  }
}

extern "C" void kernel_launch(void* const* d_in, const int* in_sizes, int n_in,
                              void* d_out, int out_size, void* d_ws, size_t ws_size,
                              hipStream_t stream) {
  const float* X     = (const float*)d_in[0];
  const float* Wihf  = (const float*)d_in[1];
  const float* Whhf  = (const float*)d_in[2];
  const float* bihf  = (const float*)d_in[3];
  const float* bhhf  = (const float*)d_in[4];
  const float* Wihb  = (const float*)d_in[5];
  const float* Whhb  = (const float*)d_in[6];
  const float* bihb  = (const float*)d_in[7];
  const float* bhhb  = (const float*)d_in[8];
  const float* Wdec  = (const float*)d_in[9];
  const float* dbih  = (const float*)d_in[10];
  const float* dbhh  = (const float*)d_in[11];
  // d_in[12..15]: attW/attW_b/attU/attU_b are mathematically dead (softmax over size-1 axis)
  const float* outW  = (const float*)d_in[16];
  const float* outWb = (const float*)d_in[17];
  float* out = (float*)d_out;

  char* ws = (char*)d_ws;
  size_t off = 0;
  auto alloc = [&](size_t bytes){ void* p = ws + off; off += (bytes + 255) & ~(size_t)255; return p; };
  ushort* preT         = (ushort*)alloc((size_t)S_*DG_*B_*2);        // 268 MB blocked [t][wgb][n][16]
  ushort* Wenc         = (ushort*)alloc((size_t)DG_*H2_*2);
  float* bsum          = (float*)alloc((size_t)DG_*4);
  uint8_t* Wp          = (uint8_t*)alloc((size_t)2*G_*E_);           // 512 KB packed fp8 Whh
  uint4* wdt           = (uint4*)alloc((size_t)64*DG_*16);
  float* bsumd         = (float*)alloc((size_t)DG_*4);
  float* SX            = (float*)alloc((size_t)B_*H2_*4);
  float* SX2           = (float*)alloc((size_t)B_*H2_*4);
  float* SH            = (float*)alloc((size_t)2*B_*E_*4);
  float* x0            = (float*)alloc((size_t)B_*H2_*4);
  float* loss_b        = (float*)alloc((size_t)B_*4);

  hipLaunchKernelGGL(k_prep_enc, dim3(DG_), dim3(512), 0, stream,
                     Wihf, Wihb, bihf, bhhf, bihb, bhhb, Wenc, bsum);
  hipLaunchKernelGGL(k_prep_whh_pk, dim3(512), dim3(64), 0, stream, Whhf, Whhb, Wp);
  hipLaunchKernelGGL(k_prep_dec, dim3(DG_), dim3(64), 0, stream, Wdec, dbih, dbhh, wdt, bsumd);
  hipLaunchKernelGGL(k_xstat, dim3(B_), dim3(H2_), 0, stream, X, SX, SX2);
  hipLaunchKernelGGL(k_gemm_pre_t, dim3(16, 512), dim3(256), 0, stream, X, Wenc, bsum, preT);
  hipLaunchKernelGGL(k_enc_mfma, dim3(16), dim3(512), 0, stream, preT, Wp, SH, x0);
  hipLaunchKernelGGL(k_dec, dim3(B_), dim3(512), 0, stream, X, wdt, bsumd, x0, SX, SX2, loss_b);
  hipLaunchKernelGGL(k_out, dim3(B_), dim3(256), 0, stream, SX, SH, outW, outWb, loss_b, out);
}

// Round 12
// 3422.709 us; speedup vs baseline: 1.4566x; 1.0783x over previous
//
#include <hip/hip_runtime.h>
#include <hip/hip_bf16.h>
#include <hip/hip_fp16.h>
#include <stdint.h>

#define B_ 128
#define S_ 512
#define E_ 256
#define H2_ 512
#define G_ 1024      // 4*E
#define DG_ 2048     // 4*H2
#define M_ (B_*S_)   // 65536

typedef float f32x4 __attribute__((ext_vector_type(4)));
typedef short s16x8 __attribute__((ext_vector_type(8)));
typedef _Float16 h16x2 __attribute__((ext_vector_type(2)));

__device__ __forceinline__ float sigm(float x){ return 1.f/(1.f+__expf(-x)); }
__device__ __forceinline__ float tanh_f(float x){ return 1.f - 2.f/(__expf(2.f*x)+1.f); }

// async global->LDS, 16B per lane (LDS dest wave-uniform base; HW adds lane*16)
__device__ __forceinline__ void gload_lds16(const void* g, void* l){
  __builtin_amdgcn_global_load_lds(
      (const __attribute__((address_space(1))) void*)g,
      (__attribute__((address_space(3))) void*)l,
      16, 0, 0);
}

// ---------------- fp8 e4m3fn encode ----------------
__device__ __forceinline__ uint32_t enc_e4m3(float f){
  uint32_t u = __float_as_uint(f);
  uint32_t s = (u >> 24) & 0x80u;
  float af = fabsf(f);
  if (!(af > 0.f)) return s;
  if (af >= 448.f) return s | 0x7Eu;
  int ex = (int)((u >> 23) & 0xFF) - 127;
  uint32_t man = u & 0x7FFFFFu;
  int bexp = ex + 7;
  if (bexp <= 0){
    uint32_t qi = (uint32_t)rintf(af * 512.f);
    if (qi > 8u) qi = 8u;
    return s | qi;
  }
  uint32_t keep = man >> 20;
  uint32_t rest = man & 0xFFFFFu;
  const uint32_t half = 0x80000u;
  if (rest > half || (rest == half && (keep & 1u))) keep++;
  if (keep == 8u){ keep = 0u; bexp++; }
  if (bexp >= 16) return s | 0x7Eu;
  if (bexp == 15 && keep == 7u) keep = 6u; // avoid NaN encoding
  return s | ((uint32_t)bexp << 3) | keep;
}

__device__ __forceinline__ uint32_t f32_to_fp8_byte(float v){
#if __has_builtin(__builtin_amdgcn_cvt_pk_fp8_f32)
  int pk = __builtin_amdgcn_cvt_pk_fp8_f32(v, v, 0, false);
  return (uint32_t)pk & 0xFFu;
#else
  return enc_e4m3(v);
#endif
}

__device__ __forceinline__ float dot2_f16(uint32_t a, uint32_t b, float acc){
#if __has_builtin(__builtin_amdgcn_fdot2)
  return __builtin_amdgcn_fdot2(__builtin_bit_cast(h16x2,a), __builtin_bit_cast(h16x2,b), acc, false);
#else
  __half2 ah = __builtin_bit_cast(__half2, a), bh = __builtin_bit_cast(__half2, b);
  float2 af = __half22float2(ah), bf = __half22float2(bh);
  return fmaf(af.x, bf.x, fmaf(af.y, bf.y, acc));
#endif
}

// ---------------- weight prep ----------------
__global__ __launch_bounds__(512) void k_prep_enc(
    const float* __restrict__ wf, const float* __restrict__ wb,
    const float* __restrict__ bihf, const float* __restrict__ bhhf,
    const float* __restrict__ bihb, const float* __restrict__ bhhb,
    ushort* __restrict__ Wenc, float* __restrict__ bsum){
  int n = blockIdx.x, d = threadIdx.x;
  const float* src = (n < G_) ? (wf + (size_t)n*H2_) : (wb + (size_t)(n-G_)*H2_);
  __hip_bfloat16 h = __float2bfloat16(src[d]);
  Wenc[(size_t)n*H2_ + d] = __builtin_bit_cast(ushort, h);
  if (d == 0) bsum[n] = (n < G_) ? (bihf[n] + bhhf[n]) : (bihb[n-G_] + bhhb[n-G_]);
}

// Whh fp8, frag-major packed for 16-wave layout. Wave wid (0..15) owns gate
// rows gt*256 + wid*16 + (lane&15), gt=0..3 (i,f,g,o) -> after MFMA each lane
// holds all 4 gates of its 4 (chain,unit) pairs. Chunk c = gt*4+p (16 KB/wave).
__global__ __launch_bounds__(64) void k_prep_whh_pk(
    const float* __restrict__ whf, const float* __restrict__ whb, uint8_t* __restrict__ Wp){
  int bid = blockIdx.x;            // 0..511 = ((d*16+wid)*4+gt)*4+p
  int lane = threadIdx.x;          // 0..63
  int d   = bid >> 8;
  int rem = bid & 255;             // wid*16 + gt*4 + p
  int wid = rem >> 4;
  int gt  = (rem >> 2) & 3;
  int p   = rem & 3;
  const float* src = d ? whb : whf;
  int row = gt*256 + wid*16 + (lane & 15);
  int hk  = (lane >> 4) * 8;
  uint8_t bytes[16];
  #pragma unroll
  for (int e = 0; e < 8; ++e){
    bytes[e]     = (uint8_t)enc_e4m3(src[(size_t)row*E_ + (2*p)*32   + hk + e]);
    bytes[8 + e] = (uint8_t)enc_e4m3(src[(size_t)row*E_ + (2*p+1)*32 + hk + e]);
  }
  uint8_t* dst = Wp + ((size_t)bid)*1024 + lane*16;
  *(uint4*)dst = *(const uint4*)bytes;
}

__global__ __launch_bounds__(64) void k_prep_dec(
    const float* __restrict__ wd, const float* __restrict__ bih, const float* __restrict__ bhh,
    uint4* __restrict__ wdt, float* __restrict__ bsumd){
  int row = blockIdx.x, u = threadIdx.x; // u in [0,64)
  const float* src = wd + (size_t)row*H2_ + u*8;
  union { _Float16 h[8]; uint4 q; } pk;
  #pragma unroll
  for (int i=0;i<8;i++) pk.h[i] = (_Float16)src[i];
  wdt[(size_t)u*DG_ + row] = pk.q;
  if (u == 0) bsumd[row] = bih[row] + bhh[row];
}

// ---------------- input stats ----------------
__global__ __launch_bounds__(512) void k_xstat(
    const float* __restrict__ X, float* __restrict__ SX, float* __restrict__ SX2){
  int b = blockIdx.x, d = threadIdx.x;
  const float* xb = X + (size_t)b*S_*H2_;
  float s=0.f, s2=0.f;
  for (int t=0;t<S_;++t){ float v = xb[(size_t)t*H2_ + d]; s += v; s2 = fmaf(v,v,s2); }
  SX[(size_t)b*H2_+d]=s; SX2[(size_t)b*H2_+d]=s2;
}

// ---------------- pre-GEMM, blocked-transposed output ----------------
// preT element ((t*8 + (b>>4))*2048 + n)*16 + (b&15); per (t, wg-of-16) tile
// contiguous; each enc wg reads its dir's 32 KB half per step.
__global__ __launch_bounds__(256) void k_gemm_pre_t(
    const float* __restrict__ X, const ushort* __restrict__ Wenc,
    const float* __restrict__ bsum, ushort* __restrict__ preT){
  __shared__ __align__(16) ushort smem[128*130];   // 33.3 KB (As|Bs then trans)
  ushort (*As)[64] = (ushort (*)[64])(smem);
  ushort (*Bs)[64] = (ushort (*)[64])(smem + 8192);
  int n0 = blockIdx.x * 128;
  int tt = blockIdx.y;
  int tid = threadIdx.x, lane = tid & 63, wq = tid >> 6;
  int wr = wq >> 1, wc = wq & 1;
  f32x4 acc[4][4] = {};
  for (int kt=0; kt<8; ++kt){
    int k0 = kt*64;
    #pragma unroll
    for (int it=0; it<4; ++it){
      int slot = tid + it*256;
      int r = slot >> 3, c8 = (slot & 7)*8;
      const float* ap = X + ((size_t)(r*512 + tt))*512 + k0 + c8;
      float4 a0 = *(const float4*)ap;
      float4 a1 = *(const float4*)(ap+4);
      union { __hip_bfloat16 h[8]; uint4 q; } pk;
      pk.h[0]=__float2bfloat16(a0.x); pk.h[1]=__float2bfloat16(a0.y);
      pk.h[2]=__float2bfloat16(a0.z); pk.h[3]=__float2bfloat16(a0.w);
      pk.h[4]=__float2bfloat16(a1.x); pk.h[5]=__float2bfloat16(a1.y);
      pk.h[6]=__float2bfloat16(a1.z); pk.h[7]=__float2bfloat16(a1.w);
      *(uint4*)&As[r][c8] = pk.q;
      *(uint4*)&Bs[r][c8] = *(const uint4*)(Wenc + (size_t)(n0+r)*512 + k0 + c8);
    }
    __syncthreads();
    #pragma unroll
    for (int kk=0; kk<2; ++kk){
      int krow = kk*32 + (lane>>4)*8;
      s16x8 af[4], bf[4];
      #pragma unroll
      for (int mi=0;mi<4;mi++) af[mi] = *(const s16x8*)&As[wr*64+mi*16+(lane&15)][krow];
      #pragma unroll
      for (int ni=0;ni<4;ni++) bf[ni] = *(const s16x8*)&Bs[wc*64+ni*16+(lane&15)][krow];
      #pragma unroll
      for (int mi=0;mi<4;mi++){
        #pragma unroll
        for (int ni=0;ni<4;ni++)
          acc[mi][ni] = __builtin_amdgcn_mfma_f32_16x16x32_bf16(af[mi], bf[ni], acc[mi][ni], 0,0,0);
      }
    }
    __syncthreads();
  }
  // epilogue: bias + bf16, C[b][n] -> smem[n_l*130 + b] (pad 130: conflict-free)
  #pragma unroll
  for (int ni=0; ni<4; ++ni){
    int n_l = wc*64 + ni*16 + (lane&15);
    float bs = bsum[n0 + n_l];
    #pragma unroll
    for (int mi=0; mi<4; ++mi){
      int bb = wr*64 + mi*16 + (lane>>4)*4;
      #pragma unroll
      for (int r2=0;r2<4;r2++){
        __hip_bfloat16 hv = __float2bfloat16(acc[mi][ni][r2] + bs);
        smem[n_l*130 + bb + r2] = __builtin_bit_cast(ushort, hv);
      }
    }
  }
  __syncthreads();
  #pragma unroll
  for (int it=0; it<64; ++it){
    int n_l = it*2 + (tid>>7);
    int b = tid & 127;
    preT[(((size_t)tt*8 + (b>>4))*2048 + n0 + n_l)*16 + (b & 15)] = smem[n_l*130 + b];
  }
}

// ---------------- encoder recurrence v12: 16 waves (4/SIMD) ----------------
// v11 structure at doubled TLP. 16 wgs x 1024 thr. Wave wid owns 64 gate rows
// (4 tiles = the 4 gates of units wid*16..wid*16+15). W: 7 chunks LDS-resident
// + 9 streamed from L2 (both laundered). pre via async global_load_lds (32 KB,
// issued at loop top, drained at the MFMA-end barrier). Gates lane-local,
// c-state 4 VGPRs. LDS 152 KB pins 1 block/CU -> full 128-VGPR budget, no spill.
__global__ __launch_bounds__(1024) void k_enc_mfma(
    const ushort* __restrict__ preT, const uint8_t* __restrict__ Wp,
    float* __restrict__ SH, float* __restrict__ x0){
  int wg = blockIdx.x;            // 0..15
  int dir = wg >> 3;
  int b0q = wg & 7;
  int b0 = b0q * 16;
  int t = threadIdx.x, lane = t & 63, wid = t >> 6;   // wid 0..15
  __shared__ __align__(16) uint4  wlds[16*7*64];    // 112 KB: W chunks 0..6 per wave
  __shared__ __align__(16) ushort pbuf[2048*8];     // 32 KB pre tile
  __shared__ __align__(16) uint8_t hb[2][16*264];   // 8.25 KB

  const uint4* wp0 = (const uint4*)(Wp + ((size_t)(dir*16 + wid))*16384);
  // one-time W stage (chunks 0..6 of this wave's 16)
  #pragma unroll
  for (int c=0; c<7; ++c)
    wlds[(wid*7 + c)*64 + lane] = wp0[c*64 + lane];
  for (int i=t; i<2*16*264; i+=1024) ((uint8_t*)hb)[i] = 0;

  int frow = lane & 15;
  int mb = (lane >> 4) * 4;
  int u0 = wid*16 + frow;
  float c_st[4] = {0,0,0,0};
  float sumh[4] = {0,0,0,0};
  __syncthreads();

  int pb = 0;
  for (int s=0; s<S_; ++s){
    int ts = dir ? (S_-1-s) : s;
    // ---- 1) async pre stage (fire-and-forget; drained at MFMA-end barrier) ----
    {
      const uint8_t* gb = (const uint8_t*)(preT + (((size_t)ts*8 + b0q)*2048 + (size_t)dir*1024)*16);
      uint8_t* lb = (uint8_t*)pbuf;
      #pragma unroll
      for (int c=0; c<2; ++c)
        gload_lds16(gb + (((wid*2 + c)*64 + lane) << 4), lb + (wid*2 + c)*1024);
    }
    // ---- 2) A-frags (fp8 h) from LDS ----
    long long a_ll[8];
    {
      const uint8_t* ar = &hb[pb][frow*264 + ((lane>>4)*8)];
      #pragma unroll
      for (int kk=0; kk<8; ++kk){
        uint2 v = *(const uint2*)(ar + kk*32);
        a_ll[kk] = (((long long)v.y) << 32) | (unsigned int)v.x;
      }
    }
    // ---- 3) MFMAs: chunks 0..6 from LDS, 7..15 from L2 (both laundered) ----
    const uint4* wl = wp0;
    const uint4* wl2 = &wlds[(wid*7)*64 + lane];
    asm volatile("" : "+v"(wl), "+v"(wl2));
    f32x4 acc[4] = {};
    #pragma unroll
    for (int gt=0; gt<4; ++gt){
      #pragma unroll
      for (int p=0; p<4; ++p){
        int c = gt*4 + p;
        uint4 q = (c < 7) ? wl2[c*64] : wl[c*64 + lane];
        long long bf0 = (((long long)q.y) << 32) | (unsigned int)q.x;
        long long bf1 = (((long long)q.w) << 32) | (unsigned int)q.z;
        acc[gt] = __builtin_amdgcn_mfma_f32_16x16x32_fp8_fp8(a_ll[2*p],   bf0, acc[gt], 0,0,0);
        acc[gt] = __builtin_amdgcn_mfma_f32_16x16x32_fp8_fp8(a_ll[2*p+1], bf1, acc[gt], 0,0,0);
      }
    }
    __syncthreads();   // drains vmcnt (pbuf ready) + all hb[pb] reads done
    // ---- 4) gates + state update, lane-local; pre from pbuf ----
    int wx0 = (dir==0 && s==S_-1) || (dir==1 && s==0);
    uint2 pvv[4];
    #pragma unroll
    for (int gt=0; gt<4; ++gt)
      pvv[gt] = *(const uint2*)&pbuf[(gt*256 + u0)*16 + mb];
    #pragma unroll
    for (int r=0; r<4; ++r){
      unsigned w0 = (r < 2) ? pvv[0].x : pvv[0].y;
      unsigned w1 = (r < 2) ? pvv[1].x : pvv[1].y;
      unsigned w2 = (r < 2) ? pvv[2].x : pvv[2].y;
      unsigned w3 = (r < 2) ? pvv[3].x : pvv[3].y;
      unsigned sh16 = (r & 1) ? 16u : 0u;
      float gi = acc[0][r] + __uint_as_float(((w0 >> sh16) & 0xFFFFu) << 16);
      float gf = acc[1][r] + __uint_as_float(((w1 >> sh16) & 0xFFFFu) << 16);
      float gg = acc[2][r] + __uint_as_float(((w2 >> sh16) & 0xFFFFu) << 16);
      float go = acc[3][r] + __uint_as_float(((w3 >> sh16) & 0xFFFFu) << 16);
      float cn = sigm(gf)*c_st[r] + sigm(gi)*tanh_f(gg);
      float hn = sigm(go)*tanh_f(cn);
      c_st[r] = cn;
      sumh[r] += hn;
      hb[pb^1][(mb+r)*264 + u0] = (uint8_t)f32_to_fp8_byte(hn);
      if (wx0) x0[(size_t)(b0+mb+r)*H2_ + dir*E_ + u0] = hn;
    }
    __syncthreads();   // hb[pb^1] + pbuf reads complete before next stage
    pb ^= 1;
  }
  #pragma unroll
  for (int r=0; r<4; ++r)
    SH[((size_t)dir*B_ + b0 + mb + r)*E_ + u0] = sumh[r];
}

// ---------------- decoder + ae_loss: 128 wgs = b, 512 thr = hidden dim ----------------
#define EPS_CONV 2e-6f
__global__ __launch_bounds__(512) void k_dec(
    const float* __restrict__ X, const uint4* __restrict__ wdt,
    const float* __restrict__ bsumd, const float* __restrict__ x0,
    const float* __restrict__ SX, const float* __restrict__ SX2,
    float* __restrict__ loss_b){
  int b = blockIdx.x, j = threadIdx.x;
  __shared__ _Float16 hl[512];
  __shared__ float red[512];
  float h = x0[(size_t)b*H2_ + j];
  hl[j] = (_Float16)h;
  float bi = bsumd[j], bg = bsumd[j+1024], bo = bsumd[j+1536];
  float sxp = 0.f, x2p = 0.f, lacc = 0.f;
  const float* xb = X + (size_t)b*S_*H2_;
  int done = S_;
  __syncthreads();
  for (int s=0; s<S_; ++s){
    float ai = bi, ag = bg, ao = bo;
    const uint4* hp = (const uint4*)hl;
    const uint4* wi = wdt + j;
    const uint4* wgp = wdt + j + 1024;
    const uint4* wo = wdt + j + 1536;
    #pragma unroll 8
    for (int u=0; u<64; ++u){
      uint4 hv = hp[u];
      uint4 a = wi[(size_t)u*DG_];
      uint4 g = wgp[(size_t)u*DG_];
      uint4 o = wo[(size_t)u*DG_];
      ai = dot2_f16(a.x, hv.x, ai); ai = dot2_f16(a.y, hv.y, ai);
      ai = dot2_f16(a.z, hv.z, ai); ai = dot2_f16(a.w, hv.w, ai);
      ag = dot2_f16(g.x, hv.x, ag); ag = dot2_f16(g.y, hv.y, ag);
      ag = dot2_f16(g.z, hv.z, ag); ag = dot2_f16(g.w, hv.w, ag);
      ao = dot2_f16(o.x, hv.x, ao); ao = dot2_f16(o.y, hv.y, ao);
      ao = dot2_f16(o.z, hv.z, ao); ao = dot2_f16(o.w, hv.w, ao);
    }
    float cc = sigm(ai) * tanh_f(ag);
    float hn = sigm(ao) * tanh_f(cc);
    float xv = xb[(size_t)s*H2_ + j];
    float dd = xv - hn;
    lacc += dd*dd; sxp += xv; x2p = fmaf(xv,xv,x2p);
    float delta = fabsf(hn - h);
    h = hn;
    __syncthreads();                      // all dot-reads of old hl done
    hl[j] = (_Float16)h;
    if (__syncthreads_count(delta > EPS_CONV) == 0){ done = s+1; break; }
  }
  if (done < S_){
    size_t o = (size_t)b*H2_ + j;
    float rx = SX[o] - sxp, rx2 = SX2[o] - x2p;
    float rem = (float)(S_ - done);
    lacc += rx2 - 2.f*h*rx + rem*h*h;
  }
  red[j] = lacc;
  __syncthreads();
  for (int st=256; st>0; st>>=1){
    if (j < st) red[j] += red[j+st];
    __syncthreads();
  }
  if (j == 0) loss_b[b] = red[0];
}

// ---------------- output head ----------------
__global__ __launch_bounds__(256) void k_out(
    const float* __restrict__ SX, const float* __restrict__ SH,
    const float* __restrict__ outW, const float* __restrict__ outWb,
    const float* __restrict__ loss_b, float* __restrict__ out){
  int b = blockIdx.x, o = threadIdx.x;
  __shared__ float pooled[512];
  for (int d=o; d<512; d+=256){
    float v = SX[(size_t)b*H2_ + d];
    v += (d < E_) ? SH[(size_t)b*E_ + d] : SH[(size_t)(B_ + b)*E_ + (d - E_)];
    pooled[d] = v;
  }
  __syncthreads();
  const float4* w4 = (const float4*)(outW + (size_t)o*H2_);
  const float4* p4 = (const float4*)pooled;
  float acc = outWb[o];
  #pragma unroll 16
  for (int i=0;i<128;i++){
    float4 w = w4[i], p = p4[i];
    acc = fmaf(w.x,p.x,acc); acc = fmaf(w.y,p.y,acc);
    acc = fmaf(w.z,p.z,acc); acc = fmaf(w.w,p.w,acc);
  }
  out[(size_t)b*256 + o] = acc;
  if (b == 0 && o == 0){
    float L = 0.f;
    for (int i=0;i<B_;i++) L += loss_b[i];
    out[32768] = L / 33554432.f;
  }
}

extern "C" void kernel_launch(void* const* d_in, const int* in_sizes, int n_in,
                              void* d_out, int out_size, void* d_ws, size_t ws_size,
                              hipStream_t stream) {
  const float* X     = (const float*)d_in[0];
  const float* Wihf  = (const float*)d_in[1];
  const float* Whhf  = (const float*)d_in[2];
  const float* bihf  = (const float*)d_in[3];
  const float* bhhf  = (const float*)d_in[4];
  const float* Wihb  = (const float*)d_in[5];
  const float* Whhb  = (const float*)d_in[6];
  const float* bihb  = (const float*)d_in[7];
  const float* bhhb  = (const float*)d_in[8];
  const float* Wdec  = (const float*)d_in[9];
  const float* dbih  = (const float*)d_in[10];
  const float* dbhh  = (const float*)d_in[11];
  // d_in[12..15]: attW/attW_b/attU/attU_b are mathematically dead (softmax over size-1 axis)
  const float* outW  = (const float*)d_in[16];
  const float* outWb = (const float*)d_in[17];
  float* out = (float*)d_out;

  char* ws = (char*)d_ws;
  size_t off = 0;
  auto alloc = [&](size_t bytes){ void* p = ws + off; off += (bytes + 255) & ~(size_t)255; return p; };
  ushort* preT         = (ushort*)alloc((size_t)S_*DG_*B_*2);        // 268 MB blocked [t][wgb][n][16]
  ushort* Wenc         = (ushort*)alloc((size_t)DG_*H2_*2);
  float* bsum          = (float*)alloc((size_t)DG_*4);
  uint8_t* Wp          = (uint8_t*)alloc((size_t)2*G_*E_);           // 512 KB packed fp8 Whh
  uint4* wdt           = (uint4*)alloc((size_t)64*DG_*16);
  float* bsumd         = (float*)alloc((size_t)DG_*4);
  float* SX            = (float*)alloc((size_t)B_*H2_*4);
  float* SX2           = (float*)alloc((size_t)B_*H2_*4);
  float* SH            = (float*)alloc((size_t)2*B_*E_*4);
  float* x0            = (float*)alloc((size_t)B_*H2_*4);
  float* loss_b        = (float*)alloc((size_t)B_*4);

  hipLaunchKernelGGL(k_prep_enc, dim3(DG_), dim3(512), 0, stream,
                     Wihf, Wihb, bihf, bhhf, bihb, bhhb, Wenc, bsum);
  hipLaunchKernelGGL(k_prep_whh_pk, dim3(512), dim3(64), 0, stream, Whhf, Whhb, Wp);
  hipLaunchKernelGGL(k_prep_dec, dim3(DG_), dim3(64), 0, stream, Wdec, dbih, dbhh, wdt, bsumd);
  hipLaunchKernelGGL(k_xstat, dim3(B_), dim3(H2_), 0, stream, X, SX, SX2);
  hipLaunchKernelGGL(k_gemm_pre_t, dim3(16, 512), dim3(256), 0, stream, X, Wenc, bsum, preT);
  hipLaunchKernelGGL(k_enc_mfma, dim3(16), dim3(1024), 0, stream, preT, Wp, SH, x0);
  hipLaunchKernelGGL(k_dec, dim3(B_), dim3(512), 0, stream, X, wdt, bsumd, x0, SX, SX2, loss_b);
  hipLaunchKernelGGL(k_out, dim3(B_), dim3(256), 0, stream, SX, SH, outW, outWb, loss_b, out);
}